// Round 1
// 550.786 us; speedup vs baseline: 1.0221x; 1.0221x over previous
//
#include <hip/hip_runtime.h>
#include <math.h>

#define N_TOKENS 16384
#define D_MODEL  4096
#define NE       64
#define NC       128
#define DELTA    0.005f
#define LIST_CAP 16384

// ---- ws layout (bytes) ---- (proven: ws_size >= FAST_NEED)
#define WS_SUMS   0          // 128 f32
#define WS_CNT    512        // int
#define WS_LIST   4096       // 16384 int
#define WS_BHI    131072     // 1 MB bf16 hi limbs [128 kc][4 kg][128 n][8 j]
#define WS_BLO    1179648    // 1 MB bf16 lo limbs, same layout
#define FAST_NEED 2228224

typedef unsigned short u16;
typedef __attribute__((ext_vector_type(8))) short short8;   // 8 bf16
typedef __attribute__((ext_vector_type(4))) float f32x4;

#define MFMA16 __builtin_amdgcn_mfma_f32_16x16x32_bf16

typedef const __attribute__((address_space(1))) void cg_void;
typedef __attribute__((address_space(3))) void lds_void;
__device__ __forceinline__ void gll16(const void* g, void* l) {
    __builtin_amdgcn_global_load_lds((cg_void*)g, (lds_void*)l, 16, 0, 0);
}

// raw global load: compiler does NOT track this vmcnt — all waits are manual.
__device__ __forceinline__ f32x4 ald16(const float* p) {
    f32x4 r;
    asm volatile("global_load_dwordx4 %0, %1, off" : "=&v"(r) : "v"(p) : "memory");
    return r;
}

#define WAITV(n) asm volatile("s_waitcnt vmcnt(" #n ")" ::: "memory")
#define WAITL0   asm volatile("s_waitcnt lgkmcnt(0)" ::: "memory")
#define SCHED0   __builtin_amdgcn_sched_barrier(0)

__device__ __forceinline__ u16 f2bf(float x) {
    unsigned u = __float_as_uint(x);
    return (u16)((u + 0x7FFFu + ((u >> 16) & 1u)) >> 16);
}
__device__ __forceinline__ float bf2f(u16 h) { return __uint_as_float(((unsigned)h) << 16); }
__device__ __forceinline__ float softplus_f(float x) {
    return (x > 0.f) ? x + log1pf(expf(-x)) : log1pf(expf(x));
}
__device__ __forceinline__ float ncdf(float z) { return 0.5f * erfcf(-z * 0.70710678118654752f); }

__global__ void k_zero(float* __restrict__ sums, int* __restrict__ cnt) {
    if (threadIdx.x < 128) sums[threadIdx.x] = 0.f;
    if (cnt != nullptr && threadIdx.x == 128) *cnt = 0;
}

// B limbs, k-major swizzle: elem offset = kc*4096 + kg*1024 + n*8 + j
// (k = kc*32 + kg*8 + j). One 8KB chunk per kc per limb, in exact gll16 lane order.
__global__ __launch_bounds__(256) void k_prep(const float* __restrict__ wg, const float* __restrict__ wn,
                                              u16* __restrict__ Bhi, u16* __restrict__ Blo) {
    __shared__ float sW[32 * 129];
    const int kc = blockIdx.x, tid = threadIdx.x;
    #pragma unroll
    for (int i = 0; i < 16; ++i) {
        const int v = tid + 256 * i;          // 4096 elems
        const int kk = v >> 7, n = v & 127;
        const int k = kc * 32 + kk;
        const float x = (n < 64) ? wg[(size_t)k * 64 + n] : wn[(size_t)k * 64 + n - 64];
        sW[kk * 129 + n] = x;
    }
    __syncthreads();
    #pragma unroll
    for (int i = 0; i < 16; ++i) {
        const int o   = tid + 256 * i;        // o = kg*1024 + n*8 + j
        const int kg  = o >> 10;
        const int rem = o & 1023;
        const int n   = rem >> 3, j = rem & 7;
        const int kk  = kg * 8 + j;
        const float x = sW[kk * 129 + n];
        const u16 h = f2bf(x);
        Bhi[(size_t)kc * 4096 + o] = h;
        Blo[(size_t)kc * 4096 + o] = f2bf(x - bf2f(h));
    }
}

// Fused split-bf16 GEMM + gating epilogue.
// 64 tokens/block, grid 256 (1 block/CU), 512 thr = 8 waves, wave tile 32x32.
// B: gll16 ring-3 (2-chunk prefetch); A: asm global loads 3 chunks ahead into
// rotating regs, limb-converted 1 chunk ahead. Raw barriers + counted vmcnt —
// loads stay in flight across barriers (T3/T4).
// LDS 64KB: Bbuf[3] 16KB each (hi 8K + lo 8K) @0; Abuf[2] 8KB each @49152.
// A limb layout: byte = kg*1024 + ((row ^ (kg<<1))*16) + j*2 (XOR kills the
// 4-way staging-write bank conflict; frag reads stay <=2-way = free).
__global__ __launch_bounds__(512, 2) void k_main(
    const float* __restrict__ inp, const u16* __restrict__ Bhi, const u16* __restrict__ Blo,
    const float* __restrict__ noise, float* __restrict__ out, float* __restrict__ sums,
    int* __restrict__ cnt, int* __restrict__ list)
{
    __shared__ __align__(16) char smem[65536];

    const int tid = threadIdx.x;
    const int l   = tid & 63;
    const int w   = tid >> 6;         // 0..7
    const int t0  = blockIdx.x * 64;
    const int m   = l & 15;
    const int q   = l >> 4;           // k-group 0..3
    const int r0  = (w & 1) * 32;     // wave row base
    const int c0  = (w >> 1) * 32;    // wave col base

    f32x4 acc00 = {0.f, 0.f, 0.f, 0.f};
    f32x4 acc01 = {0.f, 0.f, 0.f, 0.f};
    f32x4 acc10 = {0.f, 0.f, 0.f, 0.f};
    f32x4 acc11 = {0.f, 0.f, 0.f, 0.f};

    // A staging: 64 rows x 8 float4; thread -> (row, k4)
    const int arow  = tid >> 3, ak4 = tid & 7;
    const int akg   = ak4 >> 1, ahalf = ak4 & 1;
    const int aoff  = akg * 1024 + ((arow ^ (akg << 1)) * 16) + ahalf * 8;
    const float* aptr = inp + (size_t)(t0 + arow) * D_MODEL + ak4 * 4;

    // B gll16: wave-uniform LDS base w*1024; per-lane global offset w*512 + l*8 elems
    const size_t bgoff = (size_t)w * 512 + (size_t)l * 8;
    const int    bloff = w * 1024;

    // frag read byte offsets
    const int aro0 = q * 1024 + (((r0 + m) ^ (q << 1)) * 16);
    const int aro1 = q * 1024 + (((r0 + 16 + m) ^ (q << 1)) * 16);
    const int bro0 = q * 2048 + (c0 + m) * 16;
    const int bro1 = q * 2048 + (c0 + 16 + m) * 16;

    char* const AB0 = smem + 49152;          // A parity-0: hi @+0, lo @+4096
    char* const AB1 = smem + 49152 + 8192;   // A parity-1

    // convert one float4 of A into hi/lo bf16 limbs and store (ds_write_b64 x2).
    auto cvtst = [&](const f32x4 v, char* const base) {
        const unsigned u0 = __float_as_uint(v.x), u1 = __float_as_uint(v.y);
        const unsigned u2 = __float_as_uint(v.z), u3 = __float_as_uint(v.w);
        const u16 l0 = f2bf(v.x - __uint_as_float(u0 & 0xFFFF0000u));
        const u16 l1 = f2bf(v.y - __uint_as_float(u1 & 0xFFFF0000u));
        const u16 l2 = f2bf(v.z - __uint_as_float(u2 & 0xFFFF0000u));
        const u16 l3 = f2bf(v.w - __uint_as_float(u3 & 0xFFFF0000u));
        uint2 hv, lv;
        hv.x = (u0 >> 16) | (u1 & 0xFFFF0000u);
        hv.y = (u2 >> 16) | (u3 & 0xFFFF0000u);
        lv.x = (unsigned)l0 | ((unsigned)l1 << 16);
        lv.y = (unsigned)l2 | ((unsigned)l3 << 16);
        *(uint2*)(base + aoff)        = hv;
        *(uint2*)(base + 4096 + aoff) = lv;
    };

    f32x4 avU, avF;

    // ---- prologue: establish invariant [A(c+1), Bh(c+1), Bl(c+1), A(c+2)] for c=0 ----
    {
        gll16(Bhi + bgoff, smem + bloff);                       // Bh0
        gll16(Blo + bgoff, smem + 8192 + bloff);                // Bl0
        f32x4 a0 = ald16(aptr);                                 // A0
        avU = ald16(aptr + 32);                                 // A1
        gll16(Bhi + 4096 + bgoff, smem + 16384 + bloff);        // Bh1
        gll16(Blo + 4096 + bgoff, smem + 16384 + 8192 + bloff); // Bl1
        avF = ald16(aptr + 64);                                 // A2
        WAITV(4);       // drains Bh0,Bl0,A0; keeps [A1,Bh1,Bl1,A2]
        SCHED0;
        cvtst(a0, AB0);
        WAITL0;
        __builtin_amdgcn_s_barrier();
    }

    // One pipeline stage. Invariant entering iter c: outstanding (old->new)
    // = [A(c+1), Bh(c+1), Bl(c+1), A(c+2)]; Bbuf[c%3] + Abuf[c&1] valid in LDS.
    auto body = [&](const int c, const int bc, f32x4& U, char* const Ard, char* const Awr) {
        if (c < 127) {
            if (c <= 125) { WAITV(3); } else { WAITV(2); }      // A(c+1) landed
            SCHED0;
            cvtst(U, Awr);                                       // A(c+1) -> other parity buf
        }
        char* const Bb = smem + bc * 16384;
        const short8 ah0 = *(const short8*)(Ard + aro0);
        const short8 ah1 = *(const short8*)(Ard + aro1);
        const short8 al0 = *(const short8*)(Ard + 4096 + aro0);
        const short8 al1 = *(const short8*)(Ard + 4096 + aro1);
        const short8 bh0 = *(const short8*)(Bb + bro0);
        const short8 bh1 = *(const short8*)(Bb + bro1);
        const short8 bl0 = *(const short8*)(Bb + 8192 + bro0);
        const short8 bl1 = *(const short8*)(Bb + 8192 + bro1);
        acc00 = MFMA16(ah0, bh0, acc00, 0, 0, 0);
        acc00 = MFMA16(ah0, bl0, acc00, 0, 0, 0);
        acc00 = MFMA16(al0, bh0, acc00, 0, 0, 0);
        acc01 = MFMA16(ah0, bh1, acc01, 0, 0, 0);
        acc01 = MFMA16(ah0, bl1, acc01, 0, 0, 0);
        acc01 = MFMA16(al0, bh1, acc01, 0, 0, 0);
        acc10 = MFMA16(ah1, bh0, acc10, 0, 0, 0);
        acc10 = MFMA16(ah1, bl0, acc10, 0, 0, 0);
        acc10 = MFMA16(al1, bh0, acc10, 0, 0, 0);
        acc11 = MFMA16(ah1, bh1, acc11, 0, 0, 0);
        acc11 = MFMA16(ah1, bl1, acc11, 0, 0, 0);
        acc11 = MFMA16(al1, bh1, acc11, 0, 0, 0);
        if (c + 2 < 128) {                                       // issue B(c+2)
            int bn = bc + 2; if (bn >= 3) bn -= 3;
            char* const Bw = smem + bn * 16384;
            const size_t go = (size_t)(c + 2) * 4096 + bgoff;
            gll16(Bhi + go, Bw + bloff);
            gll16(Blo + go, Bw + 8192 + bloff);
        }
        if (c + 3 < 128) U = ald16(aptr + (c + 3) * 32);         // issue A(c+3)
        // drain B(c+1) (and nothing newer) before handing buffer to next iter
        if (c <= 124)      { WAITV(4); }
        else if (c == 125) { WAITV(3); }
        else if (c == 126) { WAITV(0); }
        if (c < 127) { WAITL0; __builtin_amdgcn_s_barrier(); }
    };

    int bc = 0;                                  // c % 3
    for (int c = 0; c < 128; c += 2) {
        body(c,     bc, avU, AB0, AB1);
        bc = (bc == 2) ? 0 : bc + 1;
        body(c + 1, bc, avF, AB1, AB0);
        bc = (bc == 2) ? 0 : bc + 1;
    }
    __syncthreads();   // GEMM LDS dead; overlay epilogue arrays

    float* const sL  = (float*)(smem);            // [64][132] = 33792 B
    float* const sN  = (float*)(smem + 33792);    // [64][68]  = 17408 B
    float* const sV1 = (float*)(smem + 51200);
    float* const sV2 = (float*)(smem + 51456);
    float* const sG0 = (float*)(smem + 51712);
    float* const sG1 = (float*)(smem + 51968);
    int*   const sI0 = (int*)(smem + 52224);
    int*   const sI1 = (int*)(smem + 52480);
    int*   const sRk = (int*)(smem + 52736);

    // C/D layout (m89-verified): col = lane&15, row = (lane>>4)*4 + reg
    #pragma unroll
    for (int r = 0; r < 4; ++r) {
        sL[(r0 +      q * 4 + r) * 132 + (c0 +      m)] = acc00[r];
        sL[(r0 +      q * 4 + r) * 132 + (c0 + 16 + m)] = acc01[r];
        sL[(r0 + 16 + q * 4 + r) * 132 + (c0 +      m)] = acc10[r];
        sL[(r0 + 16 + q * 4 + r) * 132 + (c0 + 16 + m)] = acc11[r];
    }

    {   // noise: 64x64 = 1024 float4, two per thread
        #pragma unroll
        for (int i = 0; i < 2; ++i) {
            const int v = tid + 512 * i;
            const int t = v >> 4, e4 = v & 15;
            *(float4*)&sN[t * 68 + e4 * 4] = *(const float4*)(noise + (size_t)(t0 + t) * NE + e4 * 4);
        }
    }
    __syncthreads();

    if (tid < 64) {
        const int t = tid, gt = t0 + t;
        float v0 = -3.4e38f, v1 = -3.4e38f, v2 = -3.4e38f;
        int i0 = 0, i1 = 0;
        #pragma unroll 4
        for (int e = 0; e < NE; ++e) {
            const float clean = sL[t * 132 + e];
            const float sd    = softplus_f(sL[t * 132 + 64 + e]) + 0.01f;
            const float ny    = fmaf(sN[t * 68 + e], sd, clean);
            if (ny > v0)      { v2 = v1; v1 = v0; i1 = i0; v0 = ny; i0 = e; }
            else if (ny > v1) { v2 = v1; v1 = ny; i1 = e; }
            else if (ny > v2) { v2 = ny; }
        }
        const float e1 = expf(v1 - v0);
        const float d  = 1.f + e1;
        const float g0 = 1.f / d, g1 = e1 / d;
        out[2 * gt + 0] = (float)i0;
        out[2 * gt + 1] = (float)i1;
        out[2 * N_TOKENS + 2 * gt + 0] = g0;
        out[2 * N_TOKENS + 2 * gt + 1] = g1;
        const int risky = ((v0 - v1) < DELTA) || ((v1 - v2) < DELTA);
        sRk[t] = risky;
        if (risky) {
            const int idx = atomicAdd(cnt, 1);
            if (idx < LIST_CAP) list[idx] = gt;
        }
        sV1[t] = v1; sV2[t] = v2; sI0[t] = i0; sI1[t] = i1; sG0[t] = g0; sG1[t] = g1;
    }
    __syncthreads();

    if (tid < 256) {
        const int e = tid & 63, h = tid >> 6;
        float loadsum = 0.f, impsum = 0.f;
        #pragma unroll 4
        for (int t = h * 16; t < h * 16 + 16; ++t) {
            if (sRk[t]) continue;
            const float clean = sL[t * 132 + e];
            const float sd    = softplus_f(sL[t * 132 + 64 + e]) + 0.01f;
            const float ny    = fmaf(sN[t * 68 + e], sd, clean);
            const float thr   = (ny > sV2[t]) ? sV2[t] : sV1[t];
            loadsum += ncdf((clean - thr) / sd);
            if (sI0[t] == e) impsum += sG0[t];
            if (sI1[t] == e) impsum += sG1[t];
        }
        atomicAdd(&sums[e], impsum);
        atomicAdd(&sums[64 + e], loadsum);
    }
}

// exact fp32 recompute for risky (near-tie) tokens; 512 thr, K split x4
__global__ __launch_bounds__(512) void k_fix(const float* __restrict__ inp,
                                             const float* __restrict__ wg,
                                             const float* __restrict__ wn,
                                             const float* __restrict__ noise,
                                             float* __restrict__ out,
                                             float* __restrict__ sums,
                                             const int* __restrict__ cnt,
                                             const int* __restrict__ list) {
    __shared__ float sRow[D_MODEL];
    __shared__ float sP[512];
    __shared__ float sLg[NC];
    __shared__ float fv1, fv2;

    const int tid = threadIdx.x;
    int n = *cnt;
    if (n > LIST_CAP) n = LIST_CAP;

    for (int it = blockIdx.x; it < n; it += gridDim.x) {
        const int tok = list[it];
        __syncthreads();
        #pragma unroll
        for (int i = 0; i < 2; ++i)
            *(float4*)&sRow[(tid + 512 * i) * 4] = *(const float4*)(inp + (size_t)tok * D_MODEL + (tid + 512 * i) * 4);
        __syncthreads();

        const int c = tid & 127, h = tid >> 7;
        const float* wcol = (c < 64) ? (wg + c) : (wn + c - 64);
        float s = 0.f;
        #pragma unroll 16
        for (int k = h * 1024; k < h * 1024 + 1024; ++k)
            s = fmaf(sRow[k], wcol[(size_t)k * 64], s);
        sP[tid] = s;
        __syncthreads();
        if (tid < 128) sLg[tid] = sP[tid] + sP[tid + 128] + sP[tid + 256] + sP[tid + 384];
        __syncthreads();

        if (tid == 0) {
            float v0 = -3.4e38f, v1 = -3.4e38f, v2 = -3.4e38f;
            int i0 = 0, i1 = 0;
            for (int e = 0; e < NE; ++e) {
                const float sd = softplus_f(sLg[64 + e]) + 0.01f;
                const float ny = fmaf(noise[(size_t)tok * NE + e], sd, sLg[e]);
                if (ny > v0)      { v2 = v1; v1 = v0; i1 = i0; v0 = ny; i0 = e; }
                else if (ny > v1) { v2 = v1; v1 = ny; i1 = e; }
                else if (ny > v2) { v2 = ny; }
            }
            const float e1 = expf(v1 - v0);
            const float d  = 1.f + e1;
            const float g0 = 1.f / d, g1 = e1 / d;
            out[2 * tok + 0] = (float)i0;
            out[2 * tok + 1] = (float)i1;
            out[2 * N_TOKENS + 2 * tok + 0] = g0;
            out[2 * N_TOKENS + 2 * tok + 1] = g1;
            atomicAdd(&sums[i0], g0);
            atomicAdd(&sums[i1], g1);
            fv1 = v1; fv2 = v2;
        }
        __syncthreads();
        if (tid < 64) {
            const int e = tid;
            const float clean = sLg[e];
            const float sd    = softplus_f(sLg[64 + e]) + 0.01f;
            const float ny    = fmaf(noise[(size_t)tok * NE + e], sd, clean);
            const float thr   = (ny > fv2) ? fv2 : fv1;
            atomicAdd(&sums[64 + e], ncdf((clean - thr) / sd));
        }
    }
}

__global__ void k_loss(const float* __restrict__ sums, float* __restrict__ out) {
    const int l = threadIdx.x;
    const float x = sums[l];
    const float y = sums[64 + l];
    float sx = x, sy = y;
    #pragma unroll
    for (int off = 32; off >= 1; off >>= 1) { sx += __shfl_xor(sx, off); sy += __shfl_xor(sy, off); }
    const float mx = sx / 64.f, my = sy / 64.f;
    const float dx = x - mx, dy = y - my;
    float vx = dx * dx, vy = dy * dy;
    #pragma unroll
    for (int off = 32; off >= 1; off >>= 1) { vx += __shfl_xor(vx, off); vy += __shfl_xor(vy, off); }
    if (l == 0)
        out[2 * N_TOKENS * 2] = (vx / 63.f) / (mx * mx + 1e-10f) + (vy / 63.f) / (my * my + 1e-10f);
}

// ---------- fallback: round-1 kernel, verbatim (uses only 512 B of ws) ----------
#define BT 32
#define BK 32
#define FBLOCK 256
__global__ __launch_bounds__(FBLOCK) void gate_fb(
    const float* __restrict__ inp, const float* __restrict__ w_gate,
    const float* __restrict__ w_noise, const float* __restrict__ noise,
    float* __restrict__ out, float* __restrict__ ws)
{
    __shared__ float sA[BT][BK + 1];
    __shared__ float sB[BK][NC];
    __shared__ float sL[BT][NC + 1];
    __shared__ float sN[BT][NE + 1];
    __shared__ float sV1[BT], sV2[BT], sG0[BT], sG1[BT];
    __shared__ int   sI0[BT], sI1[BT];

    const int tid = threadIdx.x;
    const int bt0 = blockIdx.x * BT;
    const int tc = tid & 15;
    const int tr = tid >> 4;

    float acc[2][8];
    #pragma unroll
    for (int i = 0; i < 2; ++i)
        #pragma unroll
        for (int j = 0; j < 8; ++j) acc[i][j] = 0.f;

    const int a_row = tid >> 3;
    const int a_c4  = tid & 7;

    for (int k0 = 0; k0 < D_MODEL; k0 += BK) {
        const float4 av = *(const float4*)(inp + (size_t)(bt0 + a_row) * D_MODEL + k0 + (a_c4 << 2));
        float4 bv[4];
        #pragma unroll
        for (int i = 0; i < 4; ++i) {
            const int v   = tid + (i << 8);
            const int row = v >> 5;
            const int c4  = v & 31;
            const float* src = (c4 < 16)
                ? (w_gate  + (size_t)(k0 + row) * NE + (c4 << 2))
                : (w_noise + (size_t)(k0 + row) * NE + ((c4 - 16) << 2));
            bv[i] = *(const float4*)src;
        }
        __syncthreads();
        sA[a_row][a_c4 * 4 + 0] = av.x;
        sA[a_row][a_c4 * 4 + 1] = av.y;
        sA[a_row][a_c4 * 4 + 2] = av.z;
        sA[a_row][a_c4 * 4 + 3] = av.w;
        #pragma unroll
        for (int i = 0; i < 4; ++i) {
            const int v   = tid + (i << 8);
            const int row = v >> 5;
            const int c4  = v & 31;
            *(float4*)&sB[row][c4 << 2] = bv[i];
        }
        __syncthreads();
        #pragma unroll
        for (int kk = 0; kk < BK; ++kk) {
            const float a0 = sA[tr * 2 + 0][kk];
            const float a1 = sA[tr * 2 + 1][kk];
            const float4 b0 = *(const float4*)&sB[kk][tc * 8 + 0];
            const float4 b1 = *(const float4*)&sB[kk][tc * 8 + 4];
            acc[0][0] = fmaf(a0, b0.x, acc[0][0]); acc[0][1] = fmaf(a0, b0.y, acc[0][1]);
            acc[0][2] = fmaf(a0, b0.z, acc[0][2]); acc[0][3] = fmaf(a0, b0.w, acc[0][3]);
            acc[0][4] = fmaf(a0, b1.x, acc[0][4]); acc[0][5] = fmaf(a0, b1.y, acc[0][5]);
            acc[0][6] = fmaf(a0, b1.z, acc[0][6]); acc[0][7] = fmaf(a0, b1.w, acc[0][7]);
            acc[1][0] = fmaf(a1, b0.x, acc[1][0]); acc[1][1] = fmaf(a1, b0.y, acc[1][1]);
            acc[1][2] = fmaf(a1, b0.z, acc[1][2]); acc[1][3] = fmaf(a1, b0.w, acc[1][3]);
            acc[1][4] = fmaf(a1, b1.x, acc[1][4]); acc[1][5] = fmaf(a1, b1.y, acc[1][5]);
            acc[1][6] = fmaf(a1, b1.z, acc[1][6]); acc[1][7] = fmaf(a1, b1.w, acc[1][7]);
        }
    }

    __syncthreads();
    #pragma unroll
    for (int i = 0; i < 2; ++i)
        #pragma unroll
        for (int j = 0; j < 8; ++j)
            sL[tr * 2 + i][tc * 8 + j] = acc[i][j];

    for (int v = tid; v < BT * NE; v += FBLOCK) {
        const int t = v >> 6, e = v & 63;
        sN[t][e] = noise[(size_t)(bt0 + t) * NE + e];
    }
    __syncthreads();

    if (tid < BT) {
        const int t  = tid;
        const int gt = bt0 + t;
        float v0 = -3.4e38f, v1 = -3.4e38f, v2 = -3.4e38f;
        int   i0 = 0, i1 = 0;
        #pragma unroll 4
        for (int e = 0; e < NE; ++e) {
            const float clean = sL[t][e];
            const float raw   = sL[t][NE + e];
            const float sd    = softplus_f(raw) + 0.01f;
            sL[t][NE + e] = sd;
            const float ny = fmaf(sN[t][e], sd, clean);
            sN[t][e] = ny;
            if (ny > v0)      { v2 = v1; v1 = v0; i1 = i0; v0 = ny; i0 = e; }
            else if (ny > v1) { v2 = v1; v1 = ny; i1 = e; }
            else if (ny > v2) { v2 = ny; }
        }
        const float e1 = expf(v1 - v0);
        const float d  = 1.f + e1;
        const float g0 = 1.f / d;
        const float g1 = e1 / d;
        out[2 * gt + 0] = (float)i0;
        out[2 * gt + 1] = (float)i1;
        out[2 * N_TOKENS + 2 * gt + 0] = g0;
        out[2 * N_TOKENS + 2 * gt + 1] = g1;
        sV1[t] = v1; sV2[t] = v2;
        sI0[t] = i0; sI1[t] = i1;
        sG0[t] = g0; sG1[t] = g1;
    }
    __syncthreads();

    if (tid < NE) {
        const int e = tid;
        float loadsum = 0.f, impsum = 0.f;
        #pragma unroll 4
        for (int t = 0; t < BT; ++t) {
            const float clean = sL[t][e];
            const float sd    = sL[t][NE + e];
            const float ny    = sN[t][e];
            const float thr   = (ny > sV2[t]) ? sV2[t] : sV1[t];
            const float z     = (clean - thr) / sd;
            loadsum += ncdf(z);
            if (sI0[t] == e) impsum += sG0[t];
            if (sI1[t] == e) impsum += sG1[t];
        }
        atomicAdd(&ws[e],      impsum);
        atomicAdd(&ws[NE + e], loadsum);
    }
}

extern "C" void kernel_launch(void* const* d_in, const int* in_sizes, int n_in,
                              void* d_out, int out_size, void* d_ws, size_t ws_size,
                              hipStream_t stream) {
    const float* inp     = (const float*)d_in[0];
    const float* w_gate  = (const float*)d_in[1];
    const float* w_noise = (const float*)d_in[2];
    const float* noise   = (const float*)d_in[3];
    float* out = (float*)d_out;

    float* sums = (float*)((char*)d_ws + WS_SUMS);
    int*   cnt  = (int*)((char*)d_ws + WS_CNT);
    int*   list = (int*)((char*)d_ws + WS_LIST);
    u16*   Bhi  = (u16*)((char*)d_ws + WS_BHI);
    u16*   Blo  = (u16*)((char*)d_ws + WS_BLO);

    if (ws_size >= (size_t)FAST_NEED) {
        k_zero<<<1, 192, 0, stream>>>(sums, cnt);
        k_prep<<<128, 256, 0, stream>>>(w_gate, w_noise, Bhi, Blo);
        k_main<<<N_TOKENS / 64, 512, 0, stream>>>(inp, Bhi, Blo, noise, out, sums, cnt, list);
        k_fix<<<1024, 512, 0, stream>>>(inp, w_gate, w_noise, noise, out, sums, cnt, list);
        k_loss<<<1, 64, 0, stream>>>(sums, out);
    } else {
        k_zero<<<1, 192, 0, stream>>>(sums, nullptr);
        gate_fb<<<N_TOKENS / BT, FBLOCK, 0, stream>>>(inp, w_gate, w_noise, noise, out, sums);
        k_loss<<<1, 64, 0, stream>>>(sums, out);
    }
}